// Round 17
// baseline (207.182 us; speedup 1.0000x reference)
//
#include <hip/hip_runtime.h>
#include <hip/hip_bf16.h>
#include <math.h>

#define B_ 4
#define N_ 2048
#define D_ 1024
#define H_ 16
#define HD_ 64

typedef __attribute__((ext_vector_type(8))) short bf16x8;
typedef __attribute__((ext_vector_type(8))) unsigned short u16x8;
typedef __attribute__((ext_vector_type(4))) float f32x4;

#define AS1(p) ((const __attribute__((address_space(1))) void*)(p))
#define AS3(p) ((__attribute__((address_space(3))) void*)(p))

__device__ inline float bf2f(unsigned short u) { return __uint_as_float(((unsigned)u) << 16); }
__device__ inline unsigned short f2bf(float f) {
  unsigned u = __float_as_uint(f);
  return (unsigned short)((u + 0x7fffu + ((u >> 16) & 1u)) >> 16);
}
__device__ inline unsigned short f2h(float f) {
  _Float16 h = (_Float16)f; unsigned short u; __builtin_memcpy(&u, &h, 2); return u;
}
__device__ inline float h2f(unsigned short u) {
  _Float16 h; __builtin_memcpy(&h, &u, 2); return (float)h;
}
__device__ inline float lseop_fast(float a, float b) {
  float mx = fmaxf(a, b), mn = fminf(a, b);
  return mx + __logf(1.f + __expf(mn - mx));
}

// ---------- merged prep: cast_x (4096 blk) | cast_w (2048) | rope (512) | wg1 (8) ----------
__global__ __launch_bounds__(256) void prep_all(
    const float* __restrict__ x, const float* __restrict__ Wq,
    const float* __restrict__ Wk, const float* __restrict__ Wv,
    const float* __restrict__ Wo, const float* __restrict__ Wg1,
    unsigned short* __restrict__ xb, unsigned short* __restrict__ Wqkv_p,
    unsigned short* __restrict__ Wo_p, unsigned short* __restrict__ Wg1p,
    float* __restrict__ ropeT) {
  const int bid = blockIdx.x;
  if (bid < 4096) {
    const int t = bid * 256 + threadIdx.x;
    float4 a = ((const float4*)x)[(size_t)t * 2];
    float4 b = ((const float4*)x)[(size_t)t * 2 + 1];
    union { unsigned short u[8]; uint4 q; } pk;
    pk.u[0] = f2bf(a.x); pk.u[1] = f2bf(a.y); pk.u[2] = f2bf(a.z); pk.u[3] = f2bf(a.w);
    pk.u[4] = f2bf(b.x); pk.u[5] = f2bf(b.y); pk.u[6] = f2bf(b.z); pk.u[7] = f2bf(b.w);
    ((uint4*)xb)[t] = pk.q;
  } else if (bid < 6144) {
    const int wb = bid - 4096;
    const int which = wb >> 9;
    const float* W = (which == 0) ? Wq : (which == 1) ? Wk : (which == 2) ? Wv : Wo;
    const int col0 = (which == 1) ? 1024 : (which == 2) ? 2048 : 0;
    const int Ntot = (which == 3) ? 1024 : 3072;
    unsigned short* dst = (which == 3) ? Wo_p : Wqkv_p;
    const int t = (wb & 511) * 256 + threadIdx.x;
    const int kg = t >> 10, n = t & 1023;
    union { unsigned short u[8]; uint4 q; } pk;
#pragma unroll
    for (int r = 0; r < 8; ++r)
      pk.u[r] = f2bf(W[(size_t)(kg * 8 + r) * 1024 + n]);
    *(uint4*)&dst[((size_t)kg * Ntot + col0 + n) * 8] = pk.q;
  } else if (bid < 6656) {
    const int t = (bid - 6144) * 256 + threadIdx.x;
    const int n = t >> 6, hd = t & 63;
    const float freq = expf((float)hd * -0.28782313662425575f);
    float s, c;
    sincosf((float)n * freq, &s, &c);
    ropeT[(size_t)n * 128 + hd] = c;
    ropeT[(size_t)n * 128 + 64 + hd] = s;
  } else {
    const int t = (bid - 6656) * 256 + threadIdx.x;  // 2048
    const int kg = t >> 4, hh = t & 15;
    union { unsigned short us[8]; u16x8 v; } pk;
#pragma unroll
    for (int r = 0; r < 8; ++r)
      pk.us[r] = f2bf(Wg1[(size_t)(kg * 8 + r) * 16 + hh]);
    *(u16x8*)&Wg1p[((size_t)kg * 16 + hh) * 8] = pk.v;
  }
}

// ---------- gate logits: tg[M][16] = x_bf @ Wg1_bf (MFMA) ----------
__global__ __launch_bounds__(256) void gate_logits(
    const unsigned short* __restrict__ x_bf, const unsigned short* __restrict__ Wg1p,
    float* __restrict__ tg) {
  __shared__ unsigned short Wl[128 * 16 * 8];  // 32 KB
  const int tid = threadIdx.x;
  const int lane = tid & 63, w = tid >> 6;
  const int lr = lane & 15, lg = lane >> 4;
#pragma unroll
  for (int u = 0; u < 8; ++u) {
    const int flat = u * 256 + tid;
    *(u16x8*)&Wl[flat * 8] = *(const u16x8*)&Wg1p[(size_t)flat * 8];
  }
  __syncthreads();
  const int row = blockIdx.x * 64 + w * 16 + lr;
  f32x4 acc = (f32x4){0.f, 0.f, 0.f, 0.f};
  for (int ks = 0; ks < 32; ++ks) {
    bf16x8 a = *(const bf16x8*)&x_bf[(size_t)row * 1024 + ks * 32 + lg * 8];
    bf16x8 b = *(const bf16x8*)&Wl[((ks * 4 + lg) * 16 + lr) * 8];
    acc = __builtin_amdgcn_mfma_f32_16x16x32_bf16(a, b, acc, 0, 0, 0);
  }
  const int orow = blockIdx.x * 64 + w * 16 + 4 * lg;
#pragma unroll
  for (int reg = 0; reg < 4; ++reg)
    tg[(size_t)(orow + reg) * 16 + lr] = acc[reg];
}

// ---------- fused QKV GEMM (2-buffer dbuf, 8x8 L2 super-tiling) ----------
// q(silu,bf16) / k(exp(k) f16 + chunk-sum T) / v(bf16)
__global__ __launch_bounds__(256) void gemm_qkv(
    const unsigned short* __restrict__ A, const unsigned short* __restrict__ Wp,
    unsigned short* __restrict__ qb, unsigned short* __restrict__ keh,
    unsigned short* __restrict__ vb, float* __restrict__ T, int M, int K) {
  const int Nn = 3072;
  __shared__ unsigned short Asm[2][128 * 32];
  __shared__ unsigned short Bsm[2][4 * 128 * 8];

  const int tid = threadIdx.x;
  const int lane = tid & 63;
  const int w = tid >> 6;
  const int nwg = gridDim.x;       // 1536
  const int cpx = nwg >> 3;        // 192
  const int orig = blockIdx.x;
  const int L = (orig & 7) * cpx + (orig >> 3);  // XCD-chunked
  // 8x8 super-tiles within the XCD chunk: A(2MB)+B(2MB) fits 4MB L2
  const int st = L >> 6;           // 0..11
  const int j = L & 63;
  const int by = (st / 3) * 8 + (j >> 3);
  const int bx = (st % 3) * 8 + (j & 7);
  const int m0 = by * 128, n0 = bx * 128;
  const int wr = w >> 1, wc = w & 1;

  f32x4 acc[4][4];
#pragma unroll
  for (int i = 0; i < 4; ++i)
#pragma unroll
    for (int jj = 0; jj < 4; ++jj) acc[i][jj] = (f32x4){0.f, 0.f, 0.f, 0.f};

  const int rA0 = w * 16 + (lane >> 2);
  const int rA1 = (w + 4) * 16 + (lane >> 2);
  const int sA0 = (lane & 3) ^ ((rA0 >> 1) & 3);
  const int sA1 = (lane & 3) ^ ((rA1 >> 1) & 3);
  const unsigned short* gA0 = A + (size_t)(m0 + rA0) * K + sA0 * 8;
  const unsigned short* gA1 = A + (size_t)(m0 + rA1) * K + sA1 * 8;
  const unsigned short* gB0 = Wp + (size_t)(w >> 1) * Nn * 8 +
                              (size_t)(n0 + (w & 1) * 64 + lane) * 8;
  const unsigned short* gB1 = Wp + (size_t)((w + 4) >> 1) * Nn * 8 +
                              (size_t)(n0 + ((w + 4) & 1) * 64 + lane) * 8;

  int offA[4], offB[4];
#pragma unroll
  for (int m = 0; m < 4; ++m) {
    const int rowf = wr * 64 + m * 16 + (lane & 15);
    const int sp = (lane >> 4) ^ ((rowf >> 1) & 3);
    offA[m] = rowf * 32 + sp * 8;
  }
#pragma unroll
  for (int n = 0; n < 4; ++n) {
    const int colf = wc * 64 + n * 16 + (lane & 15);
    offB[n] = (lane >> 4) * 1024 + colf * 8;
  }

  auto STAGE = [&](int buf, int t) {
    const int kt = t * 32;
    const size_t kB = (size_t)(kt >> 3) * Nn * 8;
    __builtin_amdgcn_global_load_lds(AS1(gA0 + kt), AS3(&Asm[buf][w * 512]), 16, 0, 0);
    __builtin_amdgcn_global_load_lds(AS1(gA1 + kt), AS3(&Asm[buf][(w + 4) * 512]), 16, 0, 0);
    __builtin_amdgcn_global_load_lds(AS1(gB0 + kB), AS3(&Bsm[buf][w * 512]), 16, 0, 0);
    __builtin_amdgcn_global_load_lds(AS1(gB1 + kB), AS3(&Bsm[buf][(w + 4) * 512]), 16, 0, 0);
  };

  const int NT = K >> 5;  // 32
  STAGE(0, 0);
  __syncthreads();
  int cur = 0;
  for (int t = 0; t < NT; ++t) {
    if (t + 1 < NT) STAGE(cur ^ 1, t + 1);
    bf16x8 af[4], bfr[4];
#pragma unroll
    for (int m = 0; m < 4; ++m) af[m] = *(const bf16x8*)&Asm[cur][offA[m]];
#pragma unroll
    for (int n = 0; n < 4; ++n) bfr[n] = *(const bf16x8*)&Bsm[cur][offB[n]];
#pragma unroll
    for (int m = 0; m < 4; ++m)
#pragma unroll
      for (int n = 0; n < 4; ++n)
        acc[m][n] = __builtin_amdgcn_mfma_f32_16x16x32_bf16(af[m], bfr[n], acc[m][n], 0, 0, 0);
    __syncthreads();
    cur ^= 1;
  }

  const int crow = (lane >> 4) * 4;
  const int ccol = lane & 15;
  const int slice = bx >> 3;  // 0=q,1=k,2=v (uniform per super-tile)
  if (slice == 1) {
    // k slice: store exp(k) (f16) + fused per-chunk exp-sum
#pragma unroll
    for (int n = 0; n < 4; ++n) {
      float se = 0.f;
#pragma unroll
      for (int m = 0; m < 4; ++m)
#pragma unroll
        for (int r = 0; r < 4; ++r) {
          float ev = __expf(acc[m][n][r]);
          se += ev;
          keh[(size_t)(m0 + wr * 64 + m * 16 + crow + r) * 1024 +
              (n0 & 1023) + wc * 64 + n * 16 + ccol] = f2h(ev);
        }
      se += __shfl_xor(se, 16);
      se += __shfl_xor(se, 32);
      if ((lane >> 4) == 0) {
        const int bb = m0 >> 11;
        const int h = ((n0 & 1023) + wc * 64) >> 6;
        const int hd = n * 16 + ccol;
        const int c = ((m0 & 2047) >> 6) + wr;
        T[(size_t)((bb * 16 + h) * 64 + hd) * 32 + c] = __logf(se);
      }
    }
  } else {
#pragma unroll
    for (int m = 0; m < 4; ++m)
#pragma unroll
      for (int n = 0; n < 4; ++n)
#pragma unroll
        for (int r = 0; r < 4; ++r) {
          float vv = acc[m][n][r];
          const size_t idx = (size_t)(m0 + wr * 64 + m * 16 + crow + r) * 1024 +
                             (n0 & 1023) + wc * 64 + n * 16 + ccol;
          if (slice == 0) {
            vv = vv / (1.f + __expf(-vv));
            qb[idx] = f2bf(vv);
          } else {
            vb[idx] = f2bf(vv);
          }
        }
  }
}

// ---------- MFMA bf16 GEMM (Wo, 2-buffer dbuf): f32 out ----------
__global__ __launch_bounds__(256) void gemm_bf16(
    const unsigned short* __restrict__ A, const unsigned short* __restrict__ Wp,
    float* __restrict__ Cf, int M, int K, int Nn) {
  __shared__ unsigned short Asm[2][128 * 32];
  __shared__ unsigned short Bsm[2][4 * 128 * 8];

  const int tid = threadIdx.x;
  const int lane = tid & 63;
  const int w = tid >> 6;
  const int nb = Nn >> 7;
  const int nwg = gridDim.x;
  const int cpx = nwg >> 3;
  int bid = blockIdx.x;
  bid = (bid & 7) * cpx + (bid >> 3);
  const int by = bid / nb, bx = bid % nb;
  const int m0 = by * 128, n0 = bx * 128;
  const int wr = w >> 1, wc = w & 1;

  f32x4 acc[4][4];
#pragma unroll
  for (int i = 0; i < 4; ++i)
#pragma unroll
    for (int j = 0; j < 4; ++j) acc[i][j] = (f32x4){0.f, 0.f, 0.f, 0.f};

  const int rA0 = w * 16 + (lane >> 2);
  const int rA1 = (w + 4) * 16 + (lane >> 2);
  const int sA0 = (lane & 3) ^ ((rA0 >> 1) & 3);
  const int sA1 = (lane & 3) ^ ((rA1 >> 1) & 3);
  const unsigned short* gA0 = A + (size_t)(m0 + rA0) * K + sA0 * 8;
  const unsigned short* gA1 = A + (size_t)(m0 + rA1) * K + sA1 * 8;
  const unsigned short* gB0 = Wp + (size_t)(w >> 1) * Nn * 8 +
                              (size_t)(n0 + (w & 1) * 64 + lane) * 8;
  const unsigned short* gB1 = Wp + (size_t)((w + 4) >> 1) * Nn * 8 +
                              (size_t)(n0 + ((w + 4) & 1) * 64 + lane) * 8;

  int offA[4], offB[4];
#pragma unroll
  for (int m = 0; m < 4; ++m) {
    const int rowf = wr * 64 + m * 16 + (lane & 15);
    const int sp = (lane >> 4) ^ ((rowf >> 1) & 3);
    offA[m] = rowf * 32 + sp * 8;
  }
#pragma unroll
  for (int n = 0; n < 4; ++n) {
    const int colf = wc * 64 + n * 16 + (lane & 15);
    offB[n] = (lane >> 4) * 1024 + colf * 8;
  }

  auto STAGE = [&](int buf, int t) {
    const int kt = t * 32;
    const size_t kB = (size_t)(kt >> 3) * Nn * 8;
    __builtin_amdgcn_global_load_lds(AS1(gA0 + kt), AS3(&Asm[buf][w * 512]), 16, 0, 0);
    __builtin_amdgcn_global_load_lds(AS1(gA1 + kt), AS3(&Asm[buf][(w + 4) * 512]), 16, 0, 0);
    __builtin_amdgcn_global_load_lds(AS1(gB0 + kB), AS3(&Bsm[buf][w * 512]), 16, 0, 0);
    __builtin_amdgcn_global_load_lds(AS1(gB1 + kB), AS3(&Bsm[buf][(w + 4) * 512]), 16, 0, 0);
  };

  const int NT = K >> 5;
  STAGE(0, 0);
  __syncthreads();
  int cur = 0;
  for (int t = 0; t < NT; ++t) {
    if (t + 1 < NT) STAGE(cur ^ 1, t + 1);
    bf16x8 af[4], bfr[4];
#pragma unroll
    for (int m = 0; m < 4; ++m) af[m] = *(const bf16x8*)&Asm[cur][offA[m]];
#pragma unroll
    for (int n = 0; n < 4; ++n) bfr[n] = *(const bf16x8*)&Bsm[cur][offB[n]];
#pragma unroll
    for (int m = 0; m < 4; ++m)
#pragma unroll
      for (int n = 0; n < 4; ++n)
        acc[m][n] = __builtin_amdgcn_mfma_f32_16x16x32_bf16(af[m], bfr[n], acc[m][n], 0, 0, 0);
    __syncthreads();
    cur ^= 1;
  }

  const int crow = (lane >> 4) * 4;
  const int ccol = lane & 15;
#pragma unroll
  for (int m = 0; m < 4; ++m)
#pragma unroll
    for (int n = 0; n < 4; ++n) {
#pragma unroll
      for (int r = 0; r < 4; ++r) {
        Cf[(size_t)(m0 + wr * 64 + m * 16 + crow + r) * Nn +
           n0 + wc * 64 + n * 16 + ccol] = acc[m][n][r];
      }
    }
}

// ---------- scan pass B: per-channel chunk-prefix LSE ----------
__global__ void scan_pass_b(const float* __restrict__ T, float* __restrict__ Pf) {
  const int ch = blockIdx.x * 256 + threadIdx.x;
  const float* t = &T[(size_t)ch * 32];
  float* p = &Pf[(size_t)ch * 32];
  float run = 0.f;
  for (int c = 0; c < 32; ++c) {
    p[c] = run;
    run = lseop_fast(run, t[c]);
  }
}

// ---------- GLA pass A (MFMA) with fused intra-chunk scan; A_l aliases G_l ----------
__global__ __launch_bounds__(256) void gla_a(
    const unsigned short* __restrict__ qs, const unsigned short* __restrict__ keh,
    const float* __restrict__ Pf, const unsigned short* __restrict__ v_bf,
    const float* __restrict__ ropeT,
    unsigned short* __restrict__ qg_p, unsigned short* __restrict__ U,
    unsigned short* __restrict__ o_bf, float* __restrict__ glast_g) {
  __shared__ unsigned short kg_l[64 * 128];     // 16 KB; reused as U_l
  __shared__ unsigned short kgT_l[128 * 72];    // 18 KB
  __shared__ unsigned short vT_l[64 * 72];      // 9 KB
  __shared__ unsigned short G_l[64 * 72];       // 9 KB; realiased as A_l after m1
  __shared__ unsigned short tot_l[4][64];       // f16 partials, 512 B
  __shared__ float glast_s[64];                 // 256 B
  unsigned short* A_l = G_l;                    // alias (barrier-protected)

  const int bid = blockIdx.x;
  const int bh = bid >> 5, c = bid & 31;
  const int b = bh >> 4, h = bh & 15;
  const int t0 = c * 64;
  const int tid = threadIdx.x;
  const int lane = tid & 63, w = tid >> 6;
  const int lr = lane & 15, lg = lane >> 4;

  const size_t qv_base = ((size_t)(b * N_ + t0) * H_ + h) * 64;

  const int jch = tid & 63, qq = tid >> 6;
  float e[16];
  {
    const float escale = __expf(-Pf[((size_t)bh * 64 + jch) * 32 + c]);
    float psum = 0.f;
#pragma unroll
    for (int i = 0; i < 16; ++i) {
      const int r = qq * 16 + i;
      float ei = h2f(keh[qv_base + (size_t)r * 1024 + jch]) * escale;
      e[i] = ei;
      psum += ei;
      float cv = ropeT[(size_t)(t0 + r) * 128 + jch];
      float sv = ropeT[(size_t)(t0 + r) * 128 + 64 + jch];
      kg_l[r * 128 + (((jch >> 3) ^ (r & 7)) << 3) + (jch & 7)] = f2bf(ei * cv);
      kg_l[r * 128 + ((((jch + 64) >> 3) ^ (r & 7)) << 3) + (jch & 7)] = f2bf(ei * sv);
    }
    tot_l[qq][jch] = f2h(psum);
  }
  {
    const int r = tid >> 2, d0 = (tid & 3) * 16;
    u16x8 a = *(const u16x8*)&v_bf[qv_base + (size_t)r * (H_ * 64) + d0];
    u16x8 b2 = *(const u16x8*)&v_bf[qv_base + (size_t)r * (H_ * 64) + d0 + 8];
#pragma unroll
    for (int ee = 0; ee < 8; ++ee) {
      vT_l[(d0 + ee) * 72 + r] = a[ee];
      vT_l[(d0 + 8 + ee) * 72 + r] = b2[ee];
    }
  }
  __syncthreads();
  {
    float off = 0.f;
    for (int p = 0; p < qq; ++p) off += h2f(tot_l[p][jch]);
    float S = off;
#pragma unroll
    for (int i = 0; i < 16; ++i) {
      S += e[i];
      G_l[(qq * 16 + i) * 72 + jch] = f2h(-__logf(1.f + S));
    }
    if (qq == 3) {
      glast_g[(size_t)bid * 64 + jch] = -__logf(1.f + S);
      glast_s[jch] = 1.f / (1.f + S);
    }
  }
  {
    const int j = tid >> 1, sh = (tid & 1) * 32;
#pragma unroll
    for (int u = 0; u < 4; ++u) {
      union { unsigned short us[8]; u16x8 v; } tv;
#pragma unroll
      for (int ee = 0; ee < 8; ++ee) {
        const int s = sh + 8 * u + ee;
        tv.us[ee] = kg_l[s * 128 + (((j >> 3) ^ (s & 7)) * 8) + (j & 7)];
      }
      *(u16x8*)&kgT_l[j * 72 + sh + 8 * u] = tv.v;
    }
  }
  __syncthreads();

  bf16x8 af[4];
  {
    const int r = 16 * w + lr;
#pragma unroll
    for (int ks = 0; ks < 4; ++ks) {
      const int jb = 32 * ks + 8 * lg;
      const int jq = jb & 63;
      u16x8 q8 = *(const u16x8*)&qs[qv_base + (size_t)r * (H_ * 64) + jq];
      u16x8 gh8 = *(const u16x8*)&G_l[r * 72 + jq];
      float4 r0 = *(const float4*)&ropeT[(size_t)(t0 + r) * 128 + jb];
      float4 r1 = *(const float4*)&ropeT[(size_t)(t0 + r) * 128 + jb + 4];
      float rr[8] = {r0.x, r0.y, r0.z, r0.w, r1.x, r1.y, r1.z, r1.w};
      union { unsigned short us[8]; bf16x8 v; u16x8 uv; } pk;
#pragma unroll
      for (int ee = 0; ee < 8; ++ee)
        pk.us[ee] = f2bf(bf2f(q8[ee]) * rr[ee] * __expf(h2f(gh8[ee])));
      af[ks] = pk.v;
      *(u16x8*)&qg_p[((((size_t)bid * 4 + w) * 4 + ks) * 64 + lane) * 8] = pk.uv;
    }
  }
  f32x4 acc1[4];
#pragma unroll
  for (int n = 0; n < 4; ++n) acc1[n] = (f32x4){0.f, 0.f, 0.f, 0.f};
#pragma unroll
  for (int n = 0; n < 4; ++n) {
    const int s = 16 * n + lr;
#pragma unroll
    for (int ks = 0; ks < 4; ++ks) {
      bf16x8 bk = *(const bf16x8*)&kg_l[s * 128 + (((lg + 4 * ks) ^ (s & 7)) * 8)];
      acc1[n] = __builtin_amdgcn_mfma_f32_16x16x32_bf16(af[ks], bk, acc1[n], 0, 0, 0);
    }
  }
  __syncthreads();  // all G_l reads done -> safe to write A_l (alias)
#pragma unroll
  for (int n = 0; n < 4; ++n) {
    const int s = 16 * n + lr;
#pragma unroll
    for (int reg = 0; reg < 4; ++reg) {
      const int cr = 16 * w + 4 * lg + reg;
      A_l[cr * 72 + s] = (s <= cr) ? f2bf(acc1[n][reg]) : (unsigned short)0;
    }
  }
  f32x4 acc2[8];
#pragma unroll
  for (int n = 0; n < 8; ++n) acc2[n] = (f32x4){0.f, 0.f, 0.f, 0.f};
#pragma unroll
  for (int ks = 0; ks < 2; ++ks) {
    const int s0 = 32 * ks + 8 * lg;
    bf16x8 av = *(const bf16x8*)&vT_l[(16 * w + lr) * 72 + s0];
#pragma unroll
    for (int n = 0; n < 8; ++n) {
      bf16x8 bk = *(const bf16x8*)&kgT_l[(16 * n + lr) * 72 + s0];
      acc2[n] = __builtin_amdgcn_mfma_f32_16x16x32_bf16(av, bk, acc2[n], 0, 0, 0);
    }
  }
  __syncthreads();
  float es[4];
#pragma unroll
  for (int n = 0; n < 4; ++n) es[n] = glast_s[16 * n + lr];
#pragma unroll
  for (int n = 0; n < 8; ++n) {
    const int j = 16 * n + lr;
    const float ee = es[n & 3];
#pragma unroll
    for (int reg = 0; reg < 4; ++reg)
      kg_l[(16 * w + 4 * lg + reg) * 128 + j] = f2bf(acc2[n][reg] * ee);
  }
  f32x4 acc3[4];
#pragma unroll
  for (int n = 0; n < 4; ++n) acc3[n] = (f32x4){0.f, 0.f, 0.f, 0.f};
#pragma unroll
  for (int ks = 0; ks < 2; ++ks) {
    const int s0 = 32 * ks + 8 * lg;
    bf16x8 aA = *(const bf16x8*)&A_l[(16 * w + lr) * 72 + s0];
#pragma unroll
    for (int n = 0; n < 4; ++n) {
      bf16x8 bV = *(const bf16x8*)&vT_l[(16 * n + lr) * 72 + s0];
      acc3[n] = __builtin_amdgcn_mfma_f32_16x16x32_bf16(aA, bV, acc3[n], 0, 0, 0);
    }
  }
#pragma unroll
  for (int n = 0; n < 4; ++n)
#pragma unroll
    for (int reg = 0; reg < 4; ++reg)
      o_bf[qv_base + (size_t)(16 * w + 4 * lg + reg) * (H_ * 64) + 16 * n + lr] =
          f2bf(acc3[n][reg]);
  __syncthreads();
#pragma unroll
  for (int u = 0; u < 4; ++u) {
    const int flat = u * 256 + tid;
    const int d = flat >> 4, sl = flat & 15;
    *(u16x8*)&U[((size_t)bid * 64 + d) * 128 + sl * 8] =
        *(const u16x8*)&kg_l[d * 128 + sl * 8];
  }
}

// ---------- GLA pass B: exclusive chunk scan (in place) ----------
__global__ __launch_bounds__(256) void gla_b(unsigned short* __restrict__ U,
                                             const float* __restrict__ glast_g) {
  const int t = blockIdx.x * 256 + threadIdx.x;
  const int j4 = t & 31;
  const int d = (t >> 5) & 63;
  const int bh = t >> 11;
  const int jj0 = (4 * j4) & 63;
  float s0 = 0.f, s1 = 0.f, s2 = 0.f, s3 = 0.f;
  for (int c = 0; c < 32; ++c) {
    const size_t ub = ((size_t)((bh * 32 + c) * 64 + d)) * 128 + 4 * j4;
    ushort4 uv = *(const ushort4*)&U[ub];
    float4 g4 = *(const float4*)&glast_g[(size_t)(bh * 32 + c) * 64 + jj0];
    ushort4 pv;
    pv.x = f2bf(s0); pv.y = f2bf(s1); pv.z = f2bf(s2); pv.w = f2bf(s3);
    *(ushort4*)&U[ub] = pv;
    s0 = s0 * __expf(g4.x) + bf2f(uv.x);
    s1 = s1 * __expf(g4.y) + bf2f(uv.y);
    s2 = s2 * __expf(g4.z) + bf2f(uv.z);
    s3 = s3 * __expf(g4.w) + bf2f(uv.w);
  }
}

// ---------- GLA pass C (MFMA): o += qg @ S_{c-1} (bf16 RMW) ----------
__global__ __launch_bounds__(256) void gla_c(
    const unsigned short* __restrict__ qg_p, const unsigned short* __restrict__ S,
    unsigned short* __restrict__ o_bf) {
  __shared__ unsigned short S_l[64 * 128];
  const int bid = blockIdx.x;
  const int bh = bid >> 5, c = bid & 31;
  const int b = bh >> 4, h = bh & 15;
  const int t0 = c * 64;
  const int tid = threadIdx.x;
  const int lane = tid & 63, w = tid >> 6;
  const int lr = lane & 15, lg = lane >> 4;
  const size_t s_base = (size_t)bid * 64 * 128;
  const size_t o_base = ((size_t)(b * N_ + t0) * H_ + h) * 64;

#pragma unroll
  for (int u = 0; u < 4; ++u) {
    const int flat = u * 256 + tid;
    const int d = flat >> 4, sl = flat & 15;
    u16x8 src = *(const u16x8*)&S[s_base + (size_t)d * 128 + sl * 8];
    *(u16x8*)&S_l[d * 128 + ((sl ^ (d & 7)) * 8)] = src;
  }
  __syncthreads();
  bf16x8 af[4];
#pragma unroll
  for (int ks = 0; ks < 4; ++ks)
    af[ks] = *(const bf16x8*)&qg_p[((((size_t)bid * 4 + w) * 4 + ks) * 64 + lane) * 8];
  f32x4 acc[4];
#pragma unroll
  for (int n = 0; n < 4; ++n) acc[n] = (f32x4){0.f, 0.f, 0.f, 0.f};
#pragma unroll
  for (int n = 0; n < 4; ++n) {
    const int d = 16 * n + lr;
#pragma unroll
    for (int ks = 0; ks < 4; ++ks) {
      bf16x8 bk = *(const bf16x8*)&S_l[d * 128 + (((lg + 4 * ks) ^ (d & 7)) * 8)];
      acc[n] = __builtin_amdgcn_mfma_f32_16x16x32_bf16(af[ks], bk, acc[n], 0, 0, 0);
    }
  }
#pragma unroll
  for (int n = 0; n < 4; ++n)
#pragma unroll
    for (int reg = 0; reg < 4; ++reg) {
      const size_t idx = o_base + (size_t)(16 * w + 4 * lg + reg) * (H_ * 64) + 16 * n + lr;
      o_bf[idx] = f2bf(bf2f(o_bf[idx]) + acc[n][reg]);
    }
}

// ---------- gate+norm: one wave per row, reduction-free gate; o in bf16 ----------
__global__ __launch_bounds__(256) void gate_norm2(
    const float* __restrict__ tg, const float* __restrict__ Wg2,
    const float* __restrict__ nw, const unsigned short* __restrict__ o_bf,
    unsigned short* __restrict__ og) {
  const int w = threadIdx.x >> 6, lane = threadIdx.x & 63;
  const int row = blockIdx.x * 4 + w;
  float tgv[16];
  const float* tp = &tg[(size_t)row * 16];
#pragma unroll
  for (int hh = 0; hh < 16; ++hh) tgv[hh] = tp[hh];
  float ogr[4][4];
  float ssq = 0.f;
#pragma unroll
  for (int u = 0; u < 4; ++u) {
    const int d0 = u * 256 + lane * 4;
    ushort4 o4 = *(const ushort4*)&o_bf[(size_t)row * 1024 + d0];
    float oa[4] = {bf2f(o4.x), bf2f(o4.y), bf2f(o4.z), bf2f(o4.w)};
    float sgx = 0.f, sgy = 0.f, sgz = 0.f, sgw = 0.f;
#pragma unroll
    for (int hh = 0; hh < 16; ++hh) {
      float4 w4 = *(const float4*)&Wg2[hh * 1024 + d0];
      sgx += tgv[hh] * w4.x; sgy += tgv[hh] * w4.y;
      sgz += tgv[hh] * w4.z; sgw += tgv[hh] * w4.w;
    }
    ogr[u][0] = oa[0] / (1.f + __expf(-sgx));
    ogr[u][1] = oa[1] / (1.f + __expf(-sgy));
    ogr[u][2] = oa[2] / (1.f + __expf(-sgz));
    ogr[u][3] = oa[3] / (1.f + __expf(-sgw));
    ssq += ogr[u][0] * ogr[u][0] + ogr[u][1] * ogr[u][1] +
           ogr[u][2] * ogr[u][2] + ogr[u][3] * ogr[u][3];
  }
#pragma unroll
  for (int off = 32; off > 0; off >>= 1) ssq += __shfl_xor(ssq, off);
  const float rinv = rsqrtf(ssq * (1.f / 1024.f) + 1e-6f);
#pragma unroll
  for (int u = 0; u < 4; ++u) {
    const int d0 = u * 256 + lane * 4;
    float4 nw4 = *(const float4*)&nw[d0];
    ushort4 st;
    st.x = f2bf(ogr[u][0] * rinv * nw4.x);
    st.y = f2bf(ogr[u][1] * rinv * nw4.y);
    st.z = f2bf(ogr[u][2] * rinv * nw4.z);
    st.w = f2bf(ogr[u][3] * rinv * nw4.w);
    *(ushort4*)&og[(size_t)row * 1024 + d0] = st;
  }
}

extern "C" void kernel_launch(void* const* d_in, const int* in_sizes, int n_in,
                              void* d_out, int out_size, void* d_ws, size_t ws_size,
                              hipStream_t stream) {
  const float* x   = (const float*)d_in[0];
  const float* Wq  = (const float*)d_in[1];
  const float* Wk  = (const float*)d_in[2];
  const float* Wv  = (const float*)d_in[3];
  const float* Wo  = (const float*)d_in[4];
  const float* Wg1 = (const float*)d_in[5];
  const float* Wg2 = (const float*)d_in[6];
  const float* nw  = (const float*)d_in[7];
  float* out = (float*)d_out;
  float* ws  = (float*)d_ws;

  const size_t P = (size_t)B_ * N_ * D_;  // 8,388,608
  unsigned short* keh = (unsigned short*)ws;              // P u16 = [0, P/2) floats
  unsigned short* o_bf = (unsigned short*)(ws + P);       // P u16
  unsigned short* qg_p = (unsigned short*)(ws + 3 * P);   // 2P u16 = [3P, 4P)
  unsigned short* U_buf = (unsigned short*)(ws + 4 * P);  // 2P u16 = [4P, 5P)
  unsigned short* v_bf = (unsigned short*)(ws + 5 * P);            // P u16
  unsigned short* q_bf = (unsigned short*)(ws + 5 * P + P / 2);    // P u16
  float* ropeT = ws + 6 * P;                                       // 262144
  float* T_buf = ws + 6 * P + 524288;                              // 131072
  float* P_buf = T_buf + 131072;                                   // 131072
  unsigned short* Wg1p = (unsigned short*)(ws + 6 * P + 786432);   // 16384 u16
  float* tg_buf = ws + 6 * P + 794624;                             // 131072
  unsigned short* x_bf = (unsigned short*)(ws + 13 * P / 2);       // P u16
  unsigned short* og_bf = x_bf;  // x_bf dead before gate_norm2 writes og
  unsigned short* Wqkv_p = (unsigned short*)(ws + 7 * P);          // 3,145,728 u16
  unsigned short* Wo_p = (unsigned short*)(ws + 7 * P + 1572864);  // 1,048,576 u16
  float* glast_g = ws + 7 * P + 2097152;                           // 131072

  const int M = B_ * N_;
  const int ggrid = (M / 128) * (D_ / 128);       // 512 (Wo)
  const int qkvgrid = (M / 128) * (3 * D_ / 128); // 1536

  prep_all<<<6664, 256, 0, stream>>>(x, Wq, Wk, Wv, Wo, Wg1,
                                     x_bf, Wqkv_p, Wo_p, Wg1p, ropeT);
  gate_logits<<<M / 64, 256, 0, stream>>>(x_bf, Wg1p, tg_buf);
  gemm_qkv<<<qkvgrid, 256, 0, stream>>>(x_bf, Wqkv_p, q_bf, keh, v_bf, T_buf, M, D_);
  scan_pass_b<<<16, 256, 0, stream>>>(T_buf, P_buf);
  gla_a<<<2048, 256, 0, stream>>>(q_bf, keh, P_buf, v_bf, ropeT, qg_p, U_buf, o_bf, glast_g);
  gla_b<<<512, 256, 0, stream>>>(U_buf, glast_g);
  gla_c<<<2048, 256, 0, stream>>>(qg_p, U_buf, o_bf);
  gate_norm2<<<M / 4, 256, 0, stream>>>(tg_buf, Wg2, nw, o_bf, og_bf);
  gemm_bf16<<<ggrid, 256, 0, stream>>>(og_bf, Wo_p, out, M, D_, D_);
}

// Round 18
// 206.584 us; speedup vs baseline: 1.0029x; 1.0029x over previous
//
#include <hip/hip_runtime.h>
#include <hip/hip_bf16.h>
#include <math.h>

#define B_ 4
#define N_ 2048
#define D_ 1024
#define H_ 16
#define HD_ 64

typedef __attribute__((ext_vector_type(8))) short bf16x8;
typedef __attribute__((ext_vector_type(8))) unsigned short u16x8;
typedef __attribute__((ext_vector_type(4))) float f32x4;

#define AS1(p) ((const __attribute__((address_space(1))) void*)(p))
#define AS3(p) ((__attribute__((address_space(3))) void*)(p))

__device__ inline float bf2f(unsigned short u) { return __uint_as_float(((unsigned)u) << 16); }
__device__ inline unsigned short f2bf(float f) {
  unsigned u = __float_as_uint(f);
  return (unsigned short)((u + 0x7fffu + ((u >> 16) & 1u)) >> 16);
}
__device__ inline unsigned short f2h(float f) {
  _Float16 h = (_Float16)f; unsigned short u; __builtin_memcpy(&u, &h, 2); return u;
}
__device__ inline float h2f(unsigned short u) {
  _Float16 h; __builtin_memcpy(&h, &u, 2); return (float)h;
}
__device__ inline float lseop_fast(float a, float b) {
  float mx = fmaxf(a, b), mn = fminf(a, b);
  return mx + __logf(1.f + __expf(mn - mx));
}

// ---------- merged prep: cast_x (4096 blk) | cast_w (2048) | rope (512) | wg1 (8) ----------
__global__ __launch_bounds__(256) void prep_all(
    const float* __restrict__ x, const float* __restrict__ Wq,
    const float* __restrict__ Wk, const float* __restrict__ Wv,
    const float* __restrict__ Wo, const float* __restrict__ Wg1,
    unsigned short* __restrict__ xb, unsigned short* __restrict__ Wqkv_p,
    unsigned short* __restrict__ Wo_p, unsigned short* __restrict__ Wg1p,
    float* __restrict__ ropeT) {
  const int bid = blockIdx.x;
  if (bid < 4096) {
    const int t = bid * 256 + threadIdx.x;
    float4 a = ((const float4*)x)[(size_t)t * 2];
    float4 b = ((const float4*)x)[(size_t)t * 2 + 1];
    union { unsigned short u[8]; uint4 q; } pk;
    pk.u[0] = f2bf(a.x); pk.u[1] = f2bf(a.y); pk.u[2] = f2bf(a.z); pk.u[3] = f2bf(a.w);
    pk.u[4] = f2bf(b.x); pk.u[5] = f2bf(b.y); pk.u[6] = f2bf(b.z); pk.u[7] = f2bf(b.w);
    ((uint4*)xb)[t] = pk.q;
  } else if (bid < 6144) {
    const int wb = bid - 4096;
    const int which = wb >> 9;
    const float* W = (which == 0) ? Wq : (which == 1) ? Wk : (which == 2) ? Wv : Wo;
    const int col0 = (which == 1) ? 1024 : (which == 2) ? 2048 : 0;
    const int Ntot = (which == 3) ? 1024 : 3072;
    unsigned short* dst = (which == 3) ? Wo_p : Wqkv_p;
    const int t = (wb & 511) * 256 + threadIdx.x;
    const int kg = t >> 10, n = t & 1023;
    union { unsigned short u[8]; uint4 q; } pk;
#pragma unroll
    for (int r = 0; r < 8; ++r)
      pk.u[r] = f2bf(W[(size_t)(kg * 8 + r) * 1024 + n]);
    *(uint4*)&dst[((size_t)kg * Ntot + col0 + n) * 8] = pk.q;
  } else if (bid < 6656) {
    const int t = (bid - 6144) * 256 + threadIdx.x;
    const int n = t >> 6, hd = t & 63;
    const float freq = expf((float)hd * -0.28782313662425575f);
    float s, c;
    sincosf((float)n * freq, &s, &c);
    ropeT[(size_t)n * 128 + hd] = c;
    ropeT[(size_t)n * 128 + 64 + hd] = s;
  } else {
    const int t = (bid - 6656) * 256 + threadIdx.x;  // 2048
    const int kg = t >> 4, hh = t & 15;
    union { unsigned short us[8]; u16x8 v; } pk;
#pragma unroll
    for (int r = 0; r < 8; ++r)
      pk.us[r] = f2bf(Wg1[(size_t)(kg * 8 + r) * 16 + hh]);
    *(u16x8*)&Wg1p[((size_t)kg * 16 + hh) * 8] = pk.v;
  }
}

// ---------- gate logits: tg[M][16] = x_bf @ Wg1_bf (MFMA) ----------
__global__ __launch_bounds__(256) void gate_logits(
    const unsigned short* __restrict__ x_bf, const unsigned short* __restrict__ Wg1p,
    float* __restrict__ tg) {
  __shared__ unsigned short Wl[128 * 16 * 8];  // 32 KB
  const int tid = threadIdx.x;
  const int lane = tid & 63, w = tid >> 6;
  const int lr = lane & 15, lg = lane >> 4;
#pragma unroll
  for (int u = 0; u < 8; ++u) {
    const int flat = u * 256 + tid;
    *(u16x8*)&Wl[flat * 8] = *(const u16x8*)&Wg1p[(size_t)flat * 8];
  }
  __syncthreads();
  const int row = blockIdx.x * 64 + w * 16 + lr;
  f32x4 acc = (f32x4){0.f, 0.f, 0.f, 0.f};
  for (int ks = 0; ks < 32; ++ks) {
    bf16x8 a = *(const bf16x8*)&x_bf[(size_t)row * 1024 + ks * 32 + lg * 8];
    bf16x8 b = *(const bf16x8*)&Wl[((ks * 4 + lg) * 16 + lr) * 8];
    acc = __builtin_amdgcn_mfma_f32_16x16x32_bf16(a, b, acc, 0, 0, 0);
  }
  const int orow = blockIdx.x * 64 + w * 16 + 4 * lg;
#pragma unroll
  for (int reg = 0; reg < 4; ++reg)
    tg[(size_t)(orow + reg) * 16 + lr] = acc[reg];
}

// ---------- fused QKV GEMM (2-buffer dbuf, 8x8 L2 super-tiling) ----------
// q(silu,bf16) / k(exp(k) f16 + chunk-sum T) / v(bf16)
__global__ __launch_bounds__(256) void gemm_qkv(
    const unsigned short* __restrict__ A, const unsigned short* __restrict__ Wp,
    unsigned short* __restrict__ qb, unsigned short* __restrict__ keh,
    unsigned short* __restrict__ vb, float* __restrict__ T, int M, int K) {
  const int Nn = 3072;
  __shared__ unsigned short Asm[2][128 * 32];
  __shared__ unsigned short Bsm[2][4 * 128 * 8];

  const int tid = threadIdx.x;
  const int lane = tid & 63;
  const int w = tid >> 6;
  const int nwg = gridDim.x;       // 1536
  const int cpx = nwg >> 3;        // 192
  const int orig = blockIdx.x;
  const int L = (orig & 7) * cpx + (orig >> 3);  // XCD-chunked
  const int st = L >> 6;           // 0..11
  const int j = L & 63;
  const int by = (st / 3) * 8 + (j >> 3);
  const int bx = (st % 3) * 8 + (j & 7);
  const int m0 = by * 128, n0 = bx * 128;
  const int wr = w >> 1, wc = w & 1;

  f32x4 acc[4][4];
#pragma unroll
  for (int i = 0; i < 4; ++i)
#pragma unroll
    for (int jj = 0; jj < 4; ++jj) acc[i][jj] = (f32x4){0.f, 0.f, 0.f, 0.f};

  const int rA0 = w * 16 + (lane >> 2);
  const int rA1 = (w + 4) * 16 + (lane >> 2);
  const int sA0 = (lane & 3) ^ ((rA0 >> 1) & 3);
  const int sA1 = (lane & 3) ^ ((rA1 >> 1) & 3);
  const unsigned short* gA0 = A + (size_t)(m0 + rA0) * K + sA0 * 8;
  const unsigned short* gA1 = A + (size_t)(m0 + rA1) * K + sA1 * 8;
  const unsigned short* gB0 = Wp + (size_t)(w >> 1) * Nn * 8 +
                              (size_t)(n0 + (w & 1) * 64 + lane) * 8;
  const unsigned short* gB1 = Wp + (size_t)((w + 4) >> 1) * Nn * 8 +
                              (size_t)(n0 + ((w + 4) & 1) * 64 + lane) * 8;

  int offA[4], offB[4];
#pragma unroll
  for (int m = 0; m < 4; ++m) {
    const int rowf = wr * 64 + m * 16 + (lane & 15);
    const int sp = (lane >> 4) ^ ((rowf >> 1) & 3);
    offA[m] = rowf * 32 + sp * 8;
  }
#pragma unroll
  for (int n = 0; n < 4; ++n) {
    const int colf = wc * 64 + n * 16 + (lane & 15);
    offB[n] = (lane >> 4) * 1024 + colf * 8;
  }

  auto STAGE = [&](int buf, int t) {
    const int kt = t * 32;
    const size_t kB = (size_t)(kt >> 3) * Nn * 8;
    __builtin_amdgcn_global_load_lds(AS1(gA0 + kt), AS3(&Asm[buf][w * 512]), 16, 0, 0);
    __builtin_amdgcn_global_load_lds(AS1(gA1 + kt), AS3(&Asm[buf][(w + 4) * 512]), 16, 0, 0);
    __builtin_amdgcn_global_load_lds(AS1(gB0 + kB), AS3(&Bsm[buf][w * 512]), 16, 0, 0);
    __builtin_amdgcn_global_load_lds(AS1(gB1 + kB), AS3(&Bsm[buf][(w + 4) * 512]), 16, 0, 0);
  };

  const int NT = K >> 5;  // 32
  STAGE(0, 0);
  __syncthreads();
  int cur = 0;
  for (int t = 0; t < NT; ++t) {
    if (t + 1 < NT) STAGE(cur ^ 1, t + 1);
    bf16x8 af[4], bfr[4];
#pragma unroll
    for (int m = 0; m < 4; ++m) af[m] = *(const bf16x8*)&Asm[cur][offA[m]];
#pragma unroll
    for (int n = 0; n < 4; ++n) bfr[n] = *(const bf16x8*)&Bsm[cur][offB[n]];
#pragma unroll
    for (int m = 0; m < 4; ++m)
#pragma unroll
      for (int n = 0; n < 4; ++n)
        acc[m][n] = __builtin_amdgcn_mfma_f32_16x16x32_bf16(af[m], bfr[n], acc[m][n], 0, 0, 0);
    __syncthreads();
    cur ^= 1;
  }

  const int crow = (lane >> 4) * 4;
  const int ccol = lane & 15;
  const int slice = bx >> 3;  // 0=q,1=k,2=v (uniform per super-tile)
  if (slice == 1) {
#pragma unroll
    for (int n = 0; n < 4; ++n) {
      float se = 0.f;
#pragma unroll
      for (int m = 0; m < 4; ++m)
#pragma unroll
        for (int r = 0; r < 4; ++r) {
          float ev = __expf(acc[m][n][r]);
          se += ev;
          keh[(size_t)(m0 + wr * 64 + m * 16 + crow + r) * 1024 +
              (n0 & 1023) + wc * 64 + n * 16 + ccol] = f2h(ev);
        }
      se += __shfl_xor(se, 16);
      se += __shfl_xor(se, 32);
      if ((lane >> 4) == 0) {
        const int bb = m0 >> 11;
        const int h = ((n0 & 1023) + wc * 64) >> 6;
        const int hd = n * 16 + ccol;
        const int c = ((m0 & 2047) >> 6) + wr;
        T[(size_t)((bb * 16 + h) * 64 + hd) * 32 + c] = __logf(se);
      }
    }
  } else {
#pragma unroll
    for (int m = 0; m < 4; ++m)
#pragma unroll
      for (int n = 0; n < 4; ++n)
#pragma unroll
        for (int r = 0; r < 4; ++r) {
          float vv = acc[m][n][r];
          const size_t idx = (size_t)(m0 + wr * 64 + m * 16 + crow + r) * 1024 +
                             (n0 & 1023) + wc * 64 + n * 16 + ccol;
          if (slice == 0) {
            vv = vv / (1.f + __expf(-vv));
            qb[idx] = f2bf(vv);
          } else {
            vb[idx] = f2bf(vv);
          }
        }
  }
}

// ---------- MFMA bf16 GEMM (Wo, 2-buffer dbuf): f32 out ----------
__global__ __launch_bounds__(256) void gemm_bf16(
    const unsigned short* __restrict__ A, const unsigned short* __restrict__ Wp,
    float* __restrict__ Cf, int M, int K, int Nn) {
  __shared__ unsigned short Asm[2][128 * 32];
  __shared__ unsigned short Bsm[2][4 * 128 * 8];

  const int tid = threadIdx.x;
  const int lane = tid & 63;
  const int w = tid >> 6;
  const int nb = Nn >> 7;
  const int nwg = gridDim.x;
  const int cpx = nwg >> 3;
  int bid = blockIdx.x;
  bid = (bid & 7) * cpx + (bid >> 3);
  const int by = bid / nb, bx = bid % nb;
  const int m0 = by * 128, n0 = bx * 128;
  const int wr = w >> 1, wc = w & 1;

  f32x4 acc[4][4];
#pragma unroll
  for (int i = 0; i < 4; ++i)
#pragma unroll
    for (int j = 0; j < 4; ++j) acc[i][j] = (f32x4){0.f, 0.f, 0.f, 0.f};

  const int rA0 = w * 16 + (lane >> 2);
  const int rA1 = (w + 4) * 16 + (lane >> 2);
  const int sA0 = (lane & 3) ^ ((rA0 >> 1) & 3);
  const int sA1 = (lane & 3) ^ ((rA1 >> 1) & 3);
  const unsigned short* gA0 = A + (size_t)(m0 + rA0) * K + sA0 * 8;
  const unsigned short* gA1 = A + (size_t)(m0 + rA1) * K + sA1 * 8;
  const unsigned short* gB0 = Wp + (size_t)(w >> 1) * Nn * 8 +
                              (size_t)(n0 + (w & 1) * 64 + lane) * 8;
  const unsigned short* gB1 = Wp + (size_t)((w + 4) >> 1) * Nn * 8 +
                              (size_t)(n0 + ((w + 4) & 1) * 64 + lane) * 8;

  int offA[4], offB[4];
#pragma unroll
  for (int m = 0; m < 4; ++m) {
    const int rowf = wr * 64 + m * 16 + (lane & 15);
    const int sp = (lane >> 4) ^ ((rowf >> 1) & 3);
    offA[m] = rowf * 32 + sp * 8;
  }
#pragma unroll
  for (int n = 0; n < 4; ++n) {
    const int colf = wc * 64 + n * 16 + (lane & 15);
    offB[n] = (lane >> 4) * 1024 + colf * 8;
  }

  auto STAGE = [&](int buf, int t) {
    const int kt = t * 32;
    const size_t kB = (size_t)(kt >> 3) * Nn * 8;
    __builtin_amdgcn_global_load_lds(AS1(gA0 + kt), AS3(&Asm[buf][w * 512]), 16, 0, 0);
    __builtin_amdgcn_global_load_lds(AS1(gA1 + kt), AS3(&Asm[buf][(w + 4) * 512]), 16, 0, 0);
    __builtin_amdgcn_global_load_lds(AS1(gB0 + kB), AS3(&Bsm[buf][w * 512]), 16, 0, 0);
    __builtin_amdgcn_global_load_lds(AS1(gB1 + kB), AS3(&Bsm[buf][(w + 4) * 512]), 16, 0, 0);
  };

  const int NT = K >> 5;
  STAGE(0, 0);
  __syncthreads();
  int cur = 0;
  for (int t = 0; t < NT; ++t) {
    if (t + 1 < NT) STAGE(cur ^ 1, t + 1);
    bf16x8 af[4], bfr[4];
#pragma unroll
    for (int m = 0; m < 4; ++m) af[m] = *(const bf16x8*)&Asm[cur][offA[m]];
#pragma unroll
    for (int n = 0; n < 4; ++n) bfr[n] = *(const bf16x8*)&Bsm[cur][offB[n]];
#pragma unroll
    for (int m = 0; m < 4; ++m)
#pragma unroll
      for (int n = 0; n < 4; ++n)
        acc[m][n] = __builtin_amdgcn_mfma_f32_16x16x32_bf16(af[m], bfr[n], acc[m][n], 0, 0, 0);
    __syncthreads();
    cur ^= 1;
  }

  const int crow = (lane >> 4) * 4;
  const int ccol = lane & 15;
#pragma unroll
  for (int m = 0; m < 4; ++m)
#pragma unroll
    for (int n = 0; n < 4; ++n) {
#pragma unroll
      for (int r = 0; r < 4; ++r) {
        Cf[(size_t)(m0 + wr * 64 + m * 16 + crow + r) * Nn +
           n0 + wc * 64 + n * 16 + ccol] = acc[m][n][r];
      }
    }
}

// ---------- scan pass B: per-channel chunk-prefix LSE ----------
__global__ void scan_pass_b(const float* __restrict__ T, float* __restrict__ Pf) {
  const int ch = blockIdx.x * 256 + threadIdx.x;
  const float* t = &T[(size_t)ch * 32];
  float* p = &Pf[(size_t)ch * 32];
  float run = 0.f;
  for (int c = 0; c < 32; ++c) {
    p[c] = run;
    run = lseop_fast(run, t[c]);
  }
}

// ---------- GLA pass A (MFMA) with fused intra-chunk scan; A_l aliases G_l ----------
// glast_g now stores EXP form: exp(Glast) = 1/(1+S)
__global__ __launch_bounds__(256) void gla_a(
    const unsigned short* __restrict__ qs, const unsigned short* __restrict__ keh,
    const float* __restrict__ Pf, const unsigned short* __restrict__ v_bf,
    const float* __restrict__ ropeT,
    unsigned short* __restrict__ qg_p, unsigned short* __restrict__ U,
    unsigned short* __restrict__ o_bf, float* __restrict__ glast_g) {
  __shared__ unsigned short kg_l[64 * 128];     // 16 KB; reused as U_l
  __shared__ unsigned short kgT_l[128 * 72];    // 18 KB
  __shared__ unsigned short vT_l[64 * 72];      // 9 KB
  __shared__ unsigned short G_l[64 * 72];       // 9 KB; -> A_l -> o redistribution
  __shared__ unsigned short tot_l[4][64];       // f16 partials, 512 B
  __shared__ float glast_s[64];                 // 256 B
  unsigned short* A_l = G_l;                    // alias (barrier-protected)

  const int bid = blockIdx.x;
  const int bh = bid >> 5, c = bid & 31;
  const int b = bh >> 4, h = bh & 15;
  const int t0 = c * 64;
  const int tid = threadIdx.x;
  const int lane = tid & 63, w = tid >> 6;
  const int lr = lane & 15, lg = lane >> 4;

  const size_t qv_base = ((size_t)(b * N_ + t0) * H_ + h) * 64;

  const int jch = tid & 63, qq = tid >> 6;
  float e[16];
  {
    const float escale = __expf(-Pf[((size_t)bh * 64 + jch) * 32 + c]);
    float psum = 0.f;
#pragma unroll
    for (int i = 0; i < 16; ++i) {
      const int r = qq * 16 + i;
      float ei = h2f(keh[qv_base + (size_t)r * 1024 + jch]) * escale;
      e[i] = ei;
      psum += ei;
      float cv = ropeT[(size_t)(t0 + r) * 128 + jch];
      float sv = ropeT[(size_t)(t0 + r) * 128 + 64 + jch];
      kg_l[r * 128 + (((jch >> 3) ^ (r & 7)) << 3) + (jch & 7)] = f2bf(ei * cv);
      kg_l[r * 128 + ((((jch + 64) >> 3) ^ (r & 7)) << 3) + (jch & 7)] = f2bf(ei * sv);
    }
    tot_l[qq][jch] = f2h(psum);
  }
  {
    const int r = tid >> 2, d0 = (tid & 3) * 16;
    u16x8 a = *(const u16x8*)&v_bf[qv_base + (size_t)r * (H_ * 64) + d0];
    u16x8 b2 = *(const u16x8*)&v_bf[qv_base + (size_t)r * (H_ * 64) + d0 + 8];
#pragma unroll
    for (int ee = 0; ee < 8; ++ee) {
      vT_l[(d0 + ee) * 72 + r] = a[ee];
      vT_l[(d0 + 8 + ee) * 72 + r] = b2[ee];
    }
  }
  __syncthreads();
  {
    float off = 0.f;
    for (int p = 0; p < qq; ++p) off += h2f(tot_l[p][jch]);
    float S = off;
#pragma unroll
    for (int i = 0; i < 16; ++i) {
      S += e[i];
      G_l[(qq * 16 + i) * 72 + jch] = f2h(-__logf(1.f + S));
    }
    if (qq == 3) {
      const float eg = 1.f / (1.f + S);  // exp(Glast)
      glast_g[(size_t)bid * 64 + jch] = eg;
      glast_s[jch] = eg;
    }
  }
  {
    const int j = tid >> 1, sh = (tid & 1) * 32;
#pragma unroll
    for (int u = 0; u < 4; ++u) {
      union { unsigned short us[8]; u16x8 v; } tv;
#pragma unroll
      for (int ee = 0; ee < 8; ++ee) {
        const int s = sh + 8 * u + ee;
        tv.us[ee] = kg_l[s * 128 + (((j >> 3) ^ (s & 7)) * 8) + (j & 7)];
      }
      *(u16x8*)&kgT_l[j * 72 + sh + 8 * u] = tv.v;
    }
  }
  __syncthreads();

  bf16x8 af[4];
  {
    const int r = 16 * w + lr;
#pragma unroll
    for (int ks = 0; ks < 4; ++ks) {
      const int jb = 32 * ks + 8 * lg;
      const int jq = jb & 63;
      u16x8 q8 = *(const u16x8*)&qs[qv_base + (size_t)r * (H_ * 64) + jq];
      u16x8 gh8 = *(const u16x8*)&G_l[r * 72 + jq];
      float4 r0 = *(const float4*)&ropeT[(size_t)(t0 + r) * 128 + jb];
      float4 r1 = *(const float4*)&ropeT[(size_t)(t0 + r) * 128 + jb + 4];
      float rr[8] = {r0.x, r0.y, r0.z, r0.w, r1.x, r1.y, r1.z, r1.w};
      union { unsigned short us[8]; bf16x8 v; u16x8 uv; } pk;
#pragma unroll
      for (int ee = 0; ee < 8; ++ee)
        pk.us[ee] = f2bf(bf2f(q8[ee]) * rr[ee] * __expf(h2f(gh8[ee])));
      af[ks] = pk.v;
      *(u16x8*)&qg_p[((((size_t)bid * 4 + w) * 4 + ks) * 64 + lane) * 8] = pk.uv;
    }
  }
  f32x4 acc1[4];
#pragma unroll
  for (int n = 0; n < 4; ++n) acc1[n] = (f32x4){0.f, 0.f, 0.f, 0.f};
#pragma unroll
  for (int n = 0; n < 4; ++n) {
    const int s = 16 * n + lr;
#pragma unroll
    for (int ks = 0; ks < 4; ++ks) {
      bf16x8 bk = *(const bf16x8*)&kg_l[s * 128 + (((lg + 4 * ks) ^ (s & 7)) * 8)];
      acc1[n] = __builtin_amdgcn_mfma_f32_16x16x32_bf16(af[ks], bk, acc1[n], 0, 0, 0);
    }
  }
  __syncthreads();  // all G_l reads done -> safe to write A_l (alias)
#pragma unroll
  for (int n = 0; n < 4; ++n) {
    const int s = 16 * n + lr;
#pragma unroll
    for (int reg = 0; reg < 4; ++reg) {
      const int cr = 16 * w + 4 * lg + reg;
      A_l[cr * 72 + s] = (s <= cr) ? f2bf(acc1[n][reg]) : (unsigned short)0;
    }
  }
  f32x4 acc2[8];
#pragma unroll
  for (int n = 0; n < 8; ++n) acc2[n] = (f32x4){0.f, 0.f, 0.f, 0.f};
#pragma unroll
  for (int ks = 0; ks < 2; ++ks) {
    const int s0 = 32 * ks + 8 * lg;
    bf16x8 av = *(const bf16x8*)&vT_l[(16 * w + lr) * 72 + s0];
#pragma unroll
    for (int n = 0; n < 8; ++n) {
      bf16x8 bk = *(const bf16x8*)&kgT_l[(16 * n + lr) * 72 + s0];
      acc2[n] = __builtin_amdgcn_mfma_f32_16x16x32_bf16(av, bk, acc2[n], 0, 0, 0);
    }
  }
  __syncthreads();
  float es[4];
#pragma unroll
  for (int n = 0; n < 4; ++n) es[n] = glast_s[16 * n + lr];
#pragma unroll
  for (int n = 0; n < 8; ++n) {
    const int j = 16 * n + lr;
    const float ee = es[n & 3];
#pragma unroll
    for (int reg = 0; reg < 4; ++reg)
      kg_l[(16 * w + 4 * lg + reg) * 128 + j] = f2bf(acc2[n][reg] * ee);
  }
  f32x4 acc3[4];
#pragma unroll
  for (int n = 0; n < 4; ++n) acc3[n] = (f32x4){0.f, 0.f, 0.f, 0.f};
#pragma unroll
  for (int ks = 0; ks < 2; ++ks) {
    const int s0 = 32 * ks + 8 * lg;
    bf16x8 aA = *(const bf16x8*)&A_l[(16 * w + lr) * 72 + s0];
#pragma unroll
    for (int n = 0; n < 4; ++n) {
      bf16x8 bV = *(const bf16x8*)&vT_l[(16 * n + lr) * 72 + s0];
      acc3[n] = __builtin_amdgcn_mfma_f32_16x16x32_bf16(aA, bV, acc3[n], 0, 0, 0);
    }
  }
  __syncthreads();  // A_l reads (m3) done -> reuse region for o redistribution
#pragma unroll
  for (int n = 0; n < 4; ++n)
#pragma unroll
    for (int reg = 0; reg < 4; ++reg)
      A_l[(16 * w + 4 * lg + reg) * 72 + 16 * n + lr] = f2bf(acc3[n][reg]);
  __syncthreads();
  // coalesced flush: o from A_l, U from kg_l
#pragma unroll
  for (int u = 0; u < 2; ++u) {
    const int flat = u * 256 + tid;           // 512 = 64 rows x 8
    const int d = flat >> 3, c8 = flat & 7;
    *(u16x8*)&o_bf[qv_base + (size_t)d * 1024 + c8 * 8] =
        *(const u16x8*)&A_l[d * 72 + c8 * 8];
  }
#pragma unroll
  for (int u = 0; u < 4; ++u) {
    const int flat = u * 256 + tid;
    const int d = flat >> 4, sl = flat & 15;
    *(u16x8*)&U[((size_t)bid * 64 + d) * 128 + sl * 8] =
        *(const u16x8*)&kg_l[d * 128 + sl * 8];
  }
}

// ---------- GLA pass B: exclusive chunk scan (in place); glast_g is exp-form ----------
__global__ __launch_bounds__(256) void gla_b(unsigned short* __restrict__ U,
                                             const float* __restrict__ glast_g) {
  const int t = blockIdx.x * 256 + threadIdx.x;
  const int j4 = t & 31;
  const int d = (t >> 5) & 63;
  const int bh = t >> 11;
  const int jj0 = (4 * j4) & 63;
  float s0 = 0.f, s1 = 0.f, s2 = 0.f, s3 = 0.f;
  for (int c = 0; c < 32; ++c) {
    const size_t ub = ((size_t)((bh * 32 + c) * 64 + d)) * 128 + 4 * j4;
    ushort4 uv = *(const ushort4*)&U[ub];
    float4 g4 = *(const float4*)&glast_g[(size_t)(bh * 32 + c) * 64 + jj0];
    ushort4 pv;
    pv.x = f2bf(s0); pv.y = f2bf(s1); pv.z = f2bf(s2); pv.w = f2bf(s3);
    *(ushort4*)&U[ub] = pv;
    s0 = s0 * g4.x + bf2f(uv.x);
    s1 = s1 * g4.y + bf2f(uv.y);
    s2 = s2 * g4.z + bf2f(uv.z);
    s3 = s3 * g4.w + bf2f(uv.w);
  }
}

// ---------- GLA pass C (MFMA): o += qg @ S_{c-1}; vectorized RMW via LDS ----------
__global__ __launch_bounds__(256) void gla_c(
    const unsigned short* __restrict__ qg_p, const unsigned short* __restrict__ S,
    unsigned short* __restrict__ o_bf) {
  __shared__ unsigned short S_l[64 * 128];  // reused as acc redistribution [64][72]
  const int bid = blockIdx.x;
  const int bh = bid >> 5, c = bid & 31;
  const int b = bh >> 4, h = bh & 15;
  const int t0 = c * 64;
  const int tid = threadIdx.x;
  const int lane = tid & 63, w = tid >> 6;
  const int lr = lane & 15, lg = lane >> 4;
  const size_t s_base = (size_t)bid * 64 * 128;
  const size_t o_base = ((size_t)(b * N_ + t0) * H_ + h) * 64;

#pragma unroll
  for (int u = 0; u < 4; ++u) {
    const int flat = u * 256 + tid;
    const int d = flat >> 4, sl = flat & 15;
    u16x8 src = *(const u16x8*)&S[s_base + (size_t)d * 128 + sl * 8];
    *(u16x8*)&S_l[d * 128 + ((sl ^ (d & 7)) * 8)] = src;
  }
  __syncthreads();
  bf16x8 af[4];
#pragma unroll
  for (int ks = 0; ks < 4; ++ks)
    af[ks] = *(const bf16x8*)&qg_p[((((size_t)bid * 4 + w) * 4 + ks) * 64 + lane) * 8];
  f32x4 acc[4];
#pragma unroll
  for (int n = 0; n < 4; ++n) acc[n] = (f32x4){0.f, 0.f, 0.f, 0.f};
#pragma unroll
  for (int n = 0; n < 4; ++n) {
    const int d = 16 * n + lr;
#pragma unroll
    for (int ks = 0; ks < 4; ++ks) {
      bf16x8 bk = *(const bf16x8*)&S_l[d * 128 + (((lg + 4 * ks) ^ (d & 7)) * 8)];
      acc[n] = __builtin_amdgcn_mfma_f32_16x16x32_bf16(af[ks], bk, acc[n], 0, 0, 0);
    }
  }
  __syncthreads();  // S_l reads done -> reuse as acc buffer
#pragma unroll
  for (int n = 0; n < 4; ++n)
#pragma unroll
    for (int reg = 0; reg < 4; ++reg)
      S_l[(16 * w + 4 * lg + reg) * 72 + 16 * n + lr] = f2bf(acc[n][reg]);
  __syncthreads();
  // vectorized RMW: 512 u16x8 lanes cover 64 rows x 64 cols
#pragma unroll
  for (int u = 0; u < 2; ++u) {
    const int flat = u * 256 + tid;
    const int d = flat >> 3, c8 = flat & 7;
    const size_t go = o_base + (size_t)d * 1024 + c8 * 8;
    u16x8 oldv = *(const u16x8*)&o_bf[go];
    u16x8 addv = *(const u16x8*)&S_l[d * 72 + c8 * 8];
    union { unsigned short us[8]; u16x8 v; } outv;
#pragma unroll
    for (int ee = 0; ee < 8; ++ee)
      outv.us[ee] = f2bf(bf2f(oldv[ee]) + bf2f(addv[ee]));
    *(u16x8*)&o_bf[go] = outv.v;
  }
}

// ---------- gate+norm: one wave per row, reduction-free gate; o in bf16 ----------
__global__ __launch_bounds__(256) void gate_norm2(
    const float* __restrict__ tg, const float* __restrict__ Wg2,
    const float* __restrict__ nw, const unsigned short* __restrict__ o_bf,
    unsigned short* __restrict__ og) {
  const int w = threadIdx.x >> 6, lane = threadIdx.x & 63;
  const int row = blockIdx.x * 4 + w;
  float tgv[16];
  const float* tp = &tg[(size_t)row * 16];
#pragma unroll
  for (int hh = 0; hh < 16; ++hh) tgv[hh] = tp[hh];
  float ogr[4][4];
  float ssq = 0.f;
#pragma unroll
  for (int u = 0; u < 4; ++u) {
    const int d0 = u * 256 + lane * 4;
    ushort4 o4 = *(const ushort4*)&o_bf[(size_t)row * 1024 + d0];
    float oa[4] = {bf2f(o4.x), bf2f(o4.y), bf2f(o4.z), bf2f(o4.w)};
    float sgx = 0.f, sgy = 0.f, sgz = 0.f, sgw = 0.f;
#pragma unroll
    for (int hh = 0; hh < 16; ++hh) {
      float4 w4 = *(const float4*)&Wg2[hh * 1024 + d0];
      sgx += tgv[hh] * w4.x; sgy += tgv[hh] * w4.y;
      sgz += tgv[hh] * w4.z; sgw += tgv[hh] * w4.w;
    }
    ogr[u][0] = oa[0] / (1.f + __expf(-sgx));
    ogr[u][1] = oa[1] / (1.f + __expf(-sgy));
    ogr[u][2] = oa[2] / (1.f + __expf(-sgz));
    ogr[u][3] = oa[3] / (1.f + __expf(-sgw));
    ssq += ogr[u][0] * ogr[u][0] + ogr[u][1] * ogr[u][1] +
           ogr[u][2] * ogr[u][2] + ogr[u][3] * ogr[u][3];
  }
#pragma unroll
  for (int off = 32; off > 0; off >>= 1) ssq += __shfl_xor(ssq, off);
  const float rinv = rsqrtf(ssq * (1.f / 1024.f) + 1e-6f);
#pragma unroll
  for (int u = 0; u < 4; ++u) {
    const int d0 = u * 256 + lane * 4;
    float4 nw4 = *(const float4*)&nw[d0];
    ushort4 st;
    st.x = f2bf(ogr[u][0] * rinv * nw4.x);
    st.y = f2bf(ogr[u][1] * rinv * nw4.y);
    st.z = f2bf(ogr[u][2] * rinv * nw4.z);
    st.w = f2bf(ogr[u][3] * rinv * nw4.w);
    *(ushort4*)&og[(size_t)row * 1024 + d0] = st;
  }
}

extern "C" void kernel_launch(void* const* d_in, const int* in_sizes, int n_in,
                              void* d_out, int out_size, void* d_ws, size_t ws_size,
                              hipStream_t stream) {
  const float* x   = (const float*)d_in[0];
  const float* Wq  = (const float*)d_in[1];
  const float* Wk  = (const float*)d_in[2];
  const float* Wv  = (const float*)d_in[3];
  const float* Wo  = (const float*)d_in[4];
  const float* Wg1 = (const float*)d_in[5];
  const float* Wg2 = (const float*)d_in[6];
  const float* nw  = (const float*)d_in[7];
  float* out = (float*)d_out;
  float* ws  = (float*)d_ws;

  const size_t P = (size_t)B_ * N_ * D_;  // 8,388,608
  unsigned short* keh = (unsigned short*)ws;              // P u16 = [0, P/2) floats
  unsigned short* o_bf = (unsigned short*)(ws + P);       // P u16
  unsigned short* qg_p = (unsigned short*)(ws + 3 * P);   // 2P u16 = [3P, 4P)
  unsigned short* U_buf = (unsigned short*)(ws + 4 * P);  // 2P u16 = [4P, 5P)
  unsigned short* v_bf = (unsigned short*)(ws + 5 * P);            // P u16
  unsigned short* q_bf = (unsigned short*)(ws + 5 * P + P / 2);    // P u16
  float* ropeT = ws + 6 * P;                                       // 262144
  float* T_buf = ws + 6 * P + 524288;                              // 131072
  float* P_buf = T_buf + 131072;                                   // 131072
  unsigned short* Wg1p = (unsigned short*)(ws + 6 * P + 786432);   // 16384 u16
  float* tg_buf = ws + 6 * P + 794624;                             // 131072
  unsigned short* x_bf = (unsigned short*)(ws + 13 * P / 2);       // P u16
  unsigned short* og_bf = x_bf;  // x_bf dead before gate_norm2 writes og
  unsigned short* Wqkv_p = (unsigned short*)(ws + 7 * P);          // 3,145,728 u16
  unsigned short* Wo_p = (unsigned short*)(ws + 7 * P + 1572864);  // 1,048,576 u16
  float* glast_g = ws + 7 * P + 2097152;                           // 131072

  const int M = B_ * N_;
  const int ggrid = (M / 128) * (D_ / 128);       // 512 (Wo)
  const int qkvgrid = (M / 128) * (3 * D_ / 128); // 1536

  prep_all<<<6664, 256, 0, stream>>>(x, Wq, Wk, Wv, Wo, Wg1,
                                     x_bf, Wqkv_p, Wo_p, Wg1p, ropeT);
  gate_logits<<<M / 64, 256, 0, stream>>>(x_bf, Wg1p, tg_buf);
  gemm_qkv<<<qkvgrid, 256, 0, stream>>>(x_bf, Wqkv_p, q_bf, keh, v_bf, T_buf, M, D_);
  scan_pass_b<<<16, 256, 0, stream>>>(T_buf, P_buf);
  gla_a<<<2048, 256, 0, stream>>>(q_bf, keh, P_buf, v_bf, ropeT, qg_p, U_buf, o_bf, glast_g);
  gla_b<<<512, 256, 0, stream>>>(U_buf, glast_g);
  gla_c<<<2048, 256, 0, stream>>>(qg_p, U_buf, o_bf);
  gate_norm2<<<M / 4, 256, 0, stream>>>(tg_buf, Wg2, nw, o_bf, og_bf);
  gemm_bf16<<<ggrid, 256, 0, stream>>>(og_bf, Wo_p, out, M, D_, D_);
}